// Round 4
// baseline (436.746 us; speedup 1.0000x reference)
//
#include <hip/hip_runtime.h>

#define B_ 32
#define CI 128
#define CO 256
#define K_DIM 1152            // 9*128
#define M_DIM 100352          // 32*56*56
#define BM 128
#define BN 256
#define BK 32
#define KTILES 36
#define HPAD 58               // 56 + halo
#define XB_OFF 589824         // byte offset of xb in ws (after wt: 1152*256*2 B)

typedef float          floatx4  __attribute__((ext_vector_type(4)));
typedef unsigned short ushortx8 __attribute__((ext_vector_type(8)));
typedef __bf16         bf16x8   __attribute__((ext_vector_type(8)));

typedef __attribute__((address_space(1))) void gas_void;
typedef __attribute__((address_space(3))) void las_void;
#define GLD16(g, l) __builtin_amdgcn_global_load_lds( \
    (gas_void*)(uintptr_t)(g), (las_void*)(l), 16, 0, 0)

__device__ __forceinline__ unsigned short bf16_rne(float f) {
    unsigned u = __builtin_bit_cast(unsigned, f);
    u += 0x7FFFu + ((u >> 16) & 1u);
    return (unsigned short)(u >> 16);
}

// ---- prepass 1: w[k][n] fp32 -> wt[n][k] bf16, LDS-tiled
__global__ void wt_transpose_kernel(const float* __restrict__ w,
                                    unsigned short* __restrict__ wt) {
    __shared__ unsigned short tile[64][65];
    const int kt = blockIdx.x * 64, nt = blockIdx.y * 64;
    #pragma unroll
    for (int i = 0; i < 16; ++i) {
        int idx = i * 256 + threadIdx.x;
        int kl = idx >> 6, nl = idx & 63;
        tile[kl][nl] = bf16_rne(w[(size_t)(kt + kl) * CO + nt + nl]);
    }
    __syncthreads();
    #pragma unroll
    for (int i = 0; i < 16; ++i) {
        int idx = i * 256 + threadIdx.x;
        int nl = idx >> 6, kl = idx & 63;
        wt[(size_t)(nt + nl) * K_DIM + kt + kl] = tile[kl][nl];
    }
}

// ---- prepass 2: x fp32 NHWC -> xb bf16 [32][58][58][128] with zero halo
__global__ void xpad_kernel(const float* __restrict__ x,
                            unsigned short* __restrict__ xb) {
    const int t   = blockIdx.x * 256 + threadIdx.x;
    const int pix = t >> 4;
    const int cc  = (t & 15) << 3;
    const int b   = pix / (HPAD * HPAD);
    const int rem = pix % (HPAD * HPAD);
    const int hp  = rem / HPAD, wp = rem % HPAD;
    ushortx8 g = {0, 0, 0, 0, 0, 0, 0, 0};
    if (hp >= 1 && hp <= 56 && wp >= 1 && wp <= 56) {
        const float* s = x + ((size_t)((b * 56 + hp - 1) * 56 + (wp - 1))) * CI + cc;
        floatx4 f0 = ((const floatx4*)s)[0];
        floatx4 f1 = ((const floatx4*)s)[1];
        #pragma unroll
        for (int e = 0; e < 4; ++e) { g[e] = bf16_rne(f0[e]); g[e + 4] = bf16_rne(f1[e]); }
    }
    *(ushortx8*)(xb + (size_t)pix * CI + cc) = g;
}

// ---- main: implicit-GEMM conv, BM=128 BN=256, 8 waves, dbuf + global_load_lds
__global__ __launch_bounds__(512, 6)
void conv_gemm_kernel(const unsigned short* __restrict__ xb,
                      const unsigned short* __restrict__ wt,
                      const float* __restrict__ bias,
                      float* __restrict__ out) {
    __shared__ unsigned short As[2][BM * BK];   // 2 x 8 KB, packed, chunk-swizzled
    __shared__ unsigned short Bs[2][BN * BK];   // 2 x 16 KB

    const int tid  = threadIdx.x;
    const int by   = blockIdx.x;             // m tile 0..783 (full N per block)
    const int wid  = tid >> 6;               // 0..7
    const int lane = tid & 63;
    const int lrow = lane & 15;
    const int quad = lane >> 4;
    const int wm   = (wid & 1) * 64;
    const int wn   = (wid >> 1) * 64;        // 0,64,128,192

    // staging: lane l -> LDS slot l (16 B) = seg-row l>>2, pos l&3; fetches
    // global chunk (pos - (row>>1)) & 3   (XOR-free swizzle; 0 conflicts R2/R3)
    const int rseg = lane >> 2;
    const int cglb = ((lane & 3) - (rseg >> 1)) & 3;

    // A: 128 rows staged by 8 waves, 16 rows/wave, 1 GLD16/thread
    const int ar = wid * 16 + rseg;
    const int m0 = by * BM + ar;
    const int b0 = m0 / 3136, r0 = m0 % 3136;
    const unsigned short* ag0 = xb + ((size_t)((b0 * HPAD + r0 / 56) * HPAD + r0 % 56)) * CI + cglb * 8;

    // B: 256 rows staged by 8 waves, 32 rows/wave, 2 GLD16/thread
    const int nr0 = wid * 32 + rseg;
    const unsigned short* bg0 = wt + (size_t)nr0 * K_DIM + cglb * 8;
    const unsigned short* bg1 = bg0 + (size_t)16 * K_DIM;

    const int ldsA  = (wid * 16) * BK;       // element offsets within a buffer
    const int ldsB0 = (wid * 32) * BK;
    const int ldsB1 = ldsB0 + 16 * BK;

    // fragment read offsets
    const int swz = ((quad + (lrow >> 1)) & 3) * 8;
    int a_idx[4], b_idx[4];
    #pragma unroll
    for (int i = 0; i < 4; ++i) {
        a_idx[i] = (wm + i * 16 + lrow) * BK + swz;
        b_idx[i] = (wn + i * 16 + lrow) * BK + swz;
    }

    floatx4 acc[4][4] = {};

    auto stage = [&](int kb, int buf) {
        const int p    = kb >> 2;                       // patch 0..8
        const int c0   = (kb & 3) << 5;
        const int aoff = (p / 3 * HPAD + p % 3) * CI + c0;
        const int boff = kb * BK;
        GLD16(ag0 + aoff, &As[buf][ldsA]);
        GLD16(bg0 + boff, &Bs[buf][ldsB0]);
        GLD16(bg1 + boff, &Bs[buf][ldsB1]);
    };

    auto compute = [&](int buf) {
        ushortx8 arv[4], brv[4];
        #pragma unroll
        for (int mi = 0; mi < 4; ++mi) arv[mi] = *(const ushortx8*)&As[buf][a_idx[mi]];
        #pragma unroll
        for (int ni = 0; ni < 4; ++ni) brv[ni] = *(const ushortx8*)&Bs[buf][b_idx[ni]];
        #pragma unroll
        for (int mi = 0; mi < 4; ++mi)
            #pragma unroll
            for (int ni = 0; ni < 4; ++ni)
                acc[mi][ni] = __builtin_amdgcn_mfma_f32_16x16x32_bf16(
                    __builtin_bit_cast(bf16x8, arv[mi]),
                    __builtin_bit_cast(bf16x8, brv[ni]),
                    acc[mi][ni], 0, 0, 0);
    };

    stage(0, 0);
    __syncthreads();
    int cur = 0;
    #pragma unroll 1
    for (int kb = 0; kb < KTILES - 1; ++kb) {
        stage(kb + 1, cur ^ 1);
        compute(cur);
        __syncthreads();
        cur ^= 1;
    }
    compute(cur);

    // epilogue: bias + store (C/D: col=lane&15, row=quad*4+r)
    float bv[4];
    #pragma unroll
    for (int ni = 0; ni < 4; ++ni)
        bv[ni] = bias[wn + ni * 16 + lrow];

    #pragma unroll
    for (int mi = 0; mi < 4; ++mi) {
        #pragma unroll
        for (int r = 0; r < 4; ++r) {
            const int row = by * BM + wm + mi * 16 + quad * 4 + r;
            float* o = out + (size_t)row * CO + wn + lrow;
            #pragma unroll
            for (int ni = 0; ni < 4; ++ni)
                o[ni * 16] = acc[mi][ni][r] + bv[ni];
        }
    }
}

extern "C" void kernel_launch(void* const* d_in, const int* in_sizes, int n_in,
                              void* d_out, int out_size, void* d_ws, size_t ws_size,
                              hipStream_t stream) {
    (void)in_sizes; (void)n_in; (void)out_size; (void)ws_size;
    const float* x    = (const float*)d_in[0];
    const float* w    = (const float*)d_in[1];
    const float* bias = (const float*)d_in[2];
    float* out = (float*)d_out;

    unsigned short* wt = (unsigned short*)d_ws;                     // bf16 [256][1152]
    unsigned short* xb = (unsigned short*)((char*)d_ws + XB_OFF);   // bf16 [32][58][58][128]

    wt_transpose_kernel<<<dim3(K_DIM / 64, CO / 64), dim3(256), 0, stream>>>(w, wt);
    xpad_kernel<<<dim3((B_ * HPAD * HPAD * 16) / 256), dim3(256), 0, stream>>>(x, xb);
    conv_gemm_kernel<<<dim3(M_DIM / BM), dim3(512), 0, stream>>>(xb, wt, bias, out);
}

// Round 5
// 212.651 us; speedup vs baseline: 2.0538x; 2.0538x over previous
//
#include <hip/hip_runtime.h>

#define B_ 32
#define CI 128
#define CO 256
#define K_DIM 1152            // 9*128
#define M_DIM 100352          // 32*56*56
#define BM 128
#define BN 256
#define BK 32
#define KTILES 36
#define HPAD 58               // 56 + halo
#define XB_OFF 589824         // byte offset of xb in ws (after wt: 1152*256*2 B)

typedef float          floatx4  __attribute__((ext_vector_type(4)));
typedef unsigned short ushortx8 __attribute__((ext_vector_type(8)));
typedef __bf16         bf16x8   __attribute__((ext_vector_type(8)));

typedef __attribute__((address_space(1))) void gas_void;
typedef __attribute__((address_space(3))) void las_void;
#define GLD16(g, l) __builtin_amdgcn_global_load_lds( \
    (gas_void*)(uintptr_t)(g), (las_void*)(l), 16, 0, 0)

__device__ __forceinline__ unsigned short bf16_rne(float f) {
    unsigned u = __builtin_bit_cast(unsigned, f);
    u += 0x7FFFu + ((u >> 16) & 1u);
    return (unsigned short)(u >> 16);
}

// ---- prepass 1: w[k][n] fp32 -> wt[n][k] bf16, LDS-tiled
__global__ void wt_transpose_kernel(const float* __restrict__ w,
                                    unsigned short* __restrict__ wt) {
    __shared__ unsigned short tile[64][65];
    const int kt = blockIdx.x * 64, nt = blockIdx.y * 64;
    #pragma unroll
    for (int i = 0; i < 16; ++i) {
        int idx = i * 256 + threadIdx.x;
        int kl = idx >> 6, nl = idx & 63;
        tile[kl][nl] = bf16_rne(w[(size_t)(kt + kl) * CO + nt + nl]);
    }
    __syncthreads();
    #pragma unroll
    for (int i = 0; i < 16; ++i) {
        int idx = i * 256 + threadIdx.x;
        int nl = idx >> 6, kl = idx & 63;
        wt[(size_t)(nt + nl) * K_DIM + kt + kl] = tile[kl][nl];
    }
}

// ---- prepass 2: x fp32 NHWC -> xb bf16 [32][58][58][128] with zero halo
__global__ void xpad_kernel(const float* __restrict__ x,
                            unsigned short* __restrict__ xb) {
    const int t   = blockIdx.x * 256 + threadIdx.x;
    const int pix = t >> 4;
    const int cc  = (t & 15) << 3;
    const int b   = pix / (HPAD * HPAD);
    const int rem = pix % (HPAD * HPAD);
    const int hp  = rem / HPAD, wp = rem % HPAD;
    ushortx8 g = {0, 0, 0, 0, 0, 0, 0, 0};
    if (hp >= 1 && hp <= 56 && wp >= 1 && wp <= 56) {
        const float* s = x + ((size_t)((b * 56 + hp - 1) * 56 + (wp - 1))) * CI + cc;
        floatx4 f0 = ((const floatx4*)s)[0];
        floatx4 f1 = ((const floatx4*)s)[1];
        #pragma unroll
        for (int e = 0; e < 4; ++e) { g[e] = bf16_rne(f0[e]); g[e + 4] = bf16_rne(f1[e]); }
    }
    *(ushortx8*)(xb + (size_t)pix * CI + cc) = g;
}

// ---- main: implicit-GEMM conv, BM=128 BN=256, 8 waves, dbuf + global_load_lds
// launch_bounds(512,4): 128 regs/lane budget -- MUST hold ~56 VGPR + 64 AGPR.
// (512,6) = 85-reg budget spilled the accumulators to scratch (R4: WRITE 747 MB).
__global__ __launch_bounds__(512, 4)
void conv_gemm_kernel(const unsigned short* __restrict__ xb,
                      const unsigned short* __restrict__ wt,
                      const float* __restrict__ bias,
                      float* __restrict__ out) {
    __shared__ unsigned short As[2][BM * BK];   // 2 x 8 KB, packed, chunk-swizzled
    __shared__ unsigned short Bs[2][BN * BK];   // 2 x 16 KB

    const int tid  = threadIdx.x;
    const int by   = blockIdx.x;             // m tile 0..783 (full N per block)
    const int wid  = tid >> 6;               // 0..7
    const int lane = tid & 63;
    const int lrow = lane & 15;
    const int quad = lane >> 4;
    const int wm   = (wid & 1) * 64;
    const int wn   = (wid >> 1) * 64;        // 0,64,128,192

    // staging: lane l -> LDS slot l (16 B) = seg-row l>>2, pos l&3; fetches
    // global chunk (pos - (row>>1)) & 3   (XOR-free swizzle; 0 conflicts R2/R3)
    const int rseg = lane >> 2;
    const int cglb = ((lane & 3) - (rseg >> 1)) & 3;

    // A: 128 rows staged by 8 waves, 16 rows/wave, 1 GLD16/thread
    const int ar = wid * 16 + rseg;
    const int m0 = by * BM + ar;
    const int b0 = m0 / 3136, r0 = m0 % 3136;
    const unsigned short* ag0 = xb + ((size_t)((b0 * HPAD + r0 / 56) * HPAD + r0 % 56)) * CI + cglb * 8;

    // B: 256 rows staged by 8 waves, 32 rows/wave, 2 GLD16/thread
    const int nr0 = wid * 32 + rseg;
    const unsigned short* bg0 = wt + (size_t)nr0 * K_DIM + cglb * 8;
    const unsigned short* bg1 = bg0 + (size_t)16 * K_DIM;

    const int ldsA  = (wid * 16) * BK;       // element offsets within a buffer
    const int ldsB0 = (wid * 32) * BK;
    const int ldsB1 = ldsB0 + 16 * BK;

    // fragment read offsets
    const int swz = ((quad + (lrow >> 1)) & 3) * 8;
    int a_idx[4], b_idx[4];
    #pragma unroll
    for (int i = 0; i < 4; ++i) {
        a_idx[i] = (wm + i * 16 + lrow) * BK + swz;
        b_idx[i] = (wn + i * 16 + lrow) * BK + swz;
    }

    floatx4 acc[4][4] = {};

    auto stage = [&](int kb, int buf) {
        const int p    = kb >> 2;                       // patch 0..8
        const int c0   = (kb & 3) << 5;
        const int aoff = (p / 3 * HPAD + p % 3) * CI + c0;
        const int boff = kb * BK;
        GLD16(ag0 + aoff, &As[buf][ldsA]);
        GLD16(bg0 + boff, &Bs[buf][ldsB0]);
        GLD16(bg1 + boff, &Bs[buf][ldsB1]);
    };

    auto compute = [&](int buf) {
        ushortx8 arv[4], brv[4];
        #pragma unroll
        for (int mi = 0; mi < 4; ++mi) arv[mi] = *(const ushortx8*)&As[buf][a_idx[mi]];
        #pragma unroll
        for (int ni = 0; ni < 4; ++ni) brv[ni] = *(const ushortx8*)&Bs[buf][b_idx[ni]];
        #pragma unroll
        for (int mi = 0; mi < 4; ++mi)
            #pragma unroll
            for (int ni = 0; ni < 4; ++ni)
                acc[mi][ni] = __builtin_amdgcn_mfma_f32_16x16x32_bf16(
                    __builtin_bit_cast(bf16x8, arv[mi]),
                    __builtin_bit_cast(bf16x8, brv[ni]),
                    acc[mi][ni], 0, 0, 0);
    };

    stage(0, 0);
    __syncthreads();
    int cur = 0;
    #pragma unroll 1
    for (int kb = 0; kb < KTILES - 1; ++kb) {
        stage(kb + 1, cur ^ 1);
        compute(cur);
        __syncthreads();
        cur ^= 1;
    }
    compute(cur);

    // epilogue: bias + store (C/D: col=lane&15, row=quad*4+r)
    float bv[4];
    #pragma unroll
    for (int ni = 0; ni < 4; ++ni)
        bv[ni] = bias[wn + ni * 16 + lrow];

    #pragma unroll
    for (int mi = 0; mi < 4; ++mi) {
        #pragma unroll
        for (int r = 0; r < 4; ++r) {
            const int row = by * BM + wm + mi * 16 + quad * 4 + r;
            float* o = out + (size_t)row * CO + wn + lrow;
            #pragma unroll
            for (int ni = 0; ni < 4; ++ni)
                o[ni * 16] = acc[mi][ni][r] + bv[ni];
        }
    }
}

extern "C" void kernel_launch(void* const* d_in, const int* in_sizes, int n_in,
                              void* d_out, int out_size, void* d_ws, size_t ws_size,
                              hipStream_t stream) {
    (void)in_sizes; (void)n_in; (void)out_size; (void)ws_size;
    const float* x    = (const float*)d_in[0];
    const float* w    = (const float*)d_in[1];
    const float* bias = (const float*)d_in[2];
    float* out = (float*)d_out;

    unsigned short* wt = (unsigned short*)d_ws;                     // bf16 [256][1152]
    unsigned short* xb = (unsigned short*)((char*)d_ws + XB_OFF);   // bf16 [32][58][58][128]

    wt_transpose_kernel<<<dim3(K_DIM / 64, CO / 64), dim3(256), 0, stream>>>(w, wt);
    xpad_kernel<<<dim3((B_ * HPAD * HPAD * 16) / 256), dim3(256), 0, stream>>>(x, xb);
    conv_gemm_kernel<<<dim3(M_DIM / BM), dim3(512), 0, stream>>>(xb, wt, bias, out);
}